// Round 3
// baseline (976.418 us; speedup 1.0000x reference)
//
#include <hip/hip_runtime.h>
#include <math.h>

namespace {
constexpr int N = 8, C = 48, H = 96, W = 72;
constexpr int HW = H * W;        // 6912
constexpr int P = N * HW;        // 55296
constexpr float BN_EPS = 1e-5f;

// ws layout (float offsets)
constexpr int WS_OY   = 0;            // 9 planes of P
constexpr int WS_OX   = 9 * P;
constexpr int WS_MK   = 18 * P;
constexpr int WS_WCAT = 27 * P;       // wcat[c][t][16]: 0..3 tm, 4..5 tr, 6..14 mk, 15 pad
constexpr int WCAT_SZ = C * 9 * 16;   // 6912
constexpr int WS_DWT  = WS_WCAT + WCAT_SZ;   // dwT[k][c][o], o contiguous
constexpr int DWT_SZ  = 9 * C * C;    // 20736
constexpr int WS_SC   = WS_DWT + DWT_SZ;     // bn scale[48]
constexpr int WS_BI   = WS_SC + C;           // bn bias2[48]
}

// ---------------------------------------------------------------------------
// Weight re-layout + BN fold.
// ---------------------------------------------------------------------------
__global__ void prep_kernel(const float* __restrict__ tm_w, const float* __restrict__ tr_w,
                            const float* __restrict__ mk_w, const float* __restrict__ dw,
                            const float* __restrict__ gamma, const float* __restrict__ beta,
                            const float* __restrict__ rmean, const float* __restrict__ rvar,
                            float* __restrict__ ws)
{
    int tid = blockIdx.x * blockDim.x + threadIdx.x;

    if (tid < WCAT_SZ) {
        int o  = tid & 15;
        int ct = tid >> 4;         // c*9 + t
        int c  = ct / 9;
        int t  = ct - c * 9;
        float v = 0.f;
        if (o < 4)       v = tm_w[(o * C + c) * 9 + t];
        else if (o < 6)  v = tr_w[((o - 4) * C + c) * 9 + t];
        else if (o < 15) v = mk_w[((o - 6) * C + c) * 9 + t];
        ws[WS_WCAT + tid] = v;
    }
    if (tid < DWT_SZ) {
        int o    = tid % C;
        int rest = tid / C;        // k*C + c
        int c    = rest % C;
        int k    = rest / C;
        ws[WS_DWT + tid] = dw[(o * C + c) * 9 + k];
    }
    if (tid < C) {
        float sc = gamma[tid] * rsqrtf(rvar[tid] + BN_EPS);
        ws[WS_SC + tid] = sc;
        ws[WS_BI + tid] = beta[tid] - rmean[tid] * sc;
    }
}

// ---------------------------------------------------------------------------
// Kernel A: 15-channel 3x3 conv. 4 threads/pixel (12 in-channels each),
// butterfly-reduced in-register across lane bits 0..1.
// ---------------------------------------------------------------------------
__global__ __launch_bounds__(256) void conv15_kernel(
    const float* __restrict__ x,
    const float* __restrict__ tm_b, const float* __restrict__ tr_b,
    const float* __restrict__ mk_b,
    float* __restrict__ ws)
{
    const float* wcat = ws + WS_WCAT;

    int tid   = blockIdx.x * 256 + threadIdx.x;   // grid is exactly 4*P threads
    int pid   = tid >> 2;
    int slice = tid & 3;
    int n  = pid / HW;
    int hw = pid - n * HW;
    int h  = hw / W;
    int w  = hw - h * W;

    float acc[15];
#pragma unroll
    for (int o = 0; o < 15; ++o) acc[o] = 0.f;

    const float* xn = x + (size_t)n * C * HW;

#pragma unroll 2
    for (int cc = 0; cc < 12; ++cc) {
        int c = slice * 12 + cc;
        const float* xc = xn + c * HW;
        float tap[9];
#pragma unroll
        for (int dy = -1; dy <= 1; ++dy) {
            int hh = h + dy;
            bool vy = (unsigned)hh < (unsigned)H;
#pragma unroll
            for (int dx = -1; dx <= 1; ++dx) {
                int ww = w + dx;
                bool v = vy && ((unsigned)ww < (unsigned)W);
                tap[(dy + 1) * 3 + (dx + 1)] = v ? xc[hh * W + ww] : 0.f;
            }
        }
#pragma unroll
        for (int t = 0; t < 9; ++t) {
            const float* wp = wcat + (c * 9 + t) * 16;
            float tv = tap[t];
#pragma unroll
            for (int o = 0; o < 15; ++o) acc[o] = fmaf(tv, wp[o], acc[o]);
        }
    }

    // reduce across 4 slices (lane bits 0..1)
#pragma unroll
    for (int o = 0; o < 15; ++o) {
        acc[o] += __shfl_xor(acc[o], 1);
        acc[o] += __shfl_xor(acc[o], 2);
    }

    float t0 = acc[0] + tm_b[0], t1 = acc[1] + tm_b[1];
    float t2 = acc[2] + tm_b[2], t3 = acc[3] + tm_b[3];
    float r0 = acc[4] + tr_b[0], r1 = acc[5] + tr_b[1];

    for (int k = slice; k < 9; k += 4) {
        float ry = (float)(k / 3) - 1.f;
        float rx = (float)(k % 3) - 1.f;
        ws[WS_OY + k * P + pid] = fmaf(t0, ry, fmaf(t1, rx, r0)) - ry;
        ws[WS_OX + k * P + pid] = fmaf(t2, ry, fmaf(t3, rx, r1)) - rx;
        ws[WS_MK + k * P + pid] = acc[6 + k] + mk_b[k];
    }
}

// ---------------------------------------------------------------------------
// Kernel B: bilinear deform-sample + contraction + BN + res + ReLU.
// 4 threads/pixel (12 in-channels each), butterfly reduce of acc[48],
// each slice writes 12 output channels.
// ---------------------------------------------------------------------------
__global__ __launch_bounds__(256) void deform_kernel(
    const float* __restrict__ x, const float* __restrict__ ws,
    float* __restrict__ out)
{
    int tid   = blockIdx.x * 256 + threadIdx.x;   // grid is exactly 4*P threads
    int pid   = tid >> 2;
    int slice = tid & 3;
    int n  = pid / HW;
    int hw = pid - n * HW;
    int h  = hw / W;
    int w  = hw - h * W;

    float acc[C];
#pragma unroll
    for (int o = 0; o < C; ++o) acc[o] = 0.f;

    const float* xn  = x + (size_t)n * C * HW;
    const float* dwT = ws + WS_DWT;

#pragma unroll 1
    for (int k = 0; k < 9; ++k) {
        float o_y = ws[WS_OY + k * P + pid];
        float o_x = ws[WS_OX + k * P + pid];
        float m   = ws[WS_MK + k * P + pid];

        float py = (float)(h + k / 3 - 1) + o_y;
        float px = (float)(w + k % 3 - 1) + o_x;

        float y0f = floorf(py), x0f = floorf(px);
        float wy = py - y0f, wx = px - x0f;
        int y0 = (int)y0f, x0 = (int)x0f;
        int y1 = y0 + 1,  x1 = x0 + 1;

        bool vy0 = (unsigned)y0 < (unsigned)H;
        bool vy1 = (unsigned)y1 < (unsigned)H;
        bool vx0 = (unsigned)x0 < (unsigned)W;
        bool vx1 = (unsigned)x1 < (unsigned)W;

        int cy0 = min(max(y0, 0), H - 1) * W;
        int cy1 = min(max(y1, 0), H - 1) * W;
        int cx0 = min(max(x0, 0), W - 1);
        int cx1 = min(max(x1, 0), W - 1);

        float a00 = (vy0 && vx0) ? (1.f - wy) * (1.f - wx) * m : 0.f;
        float a01 = (vy0 && vx1) ? (1.f - wy) * wx * m         : 0.f;
        float a10 = (vy1 && vx0) ? wy * (1.f - wx) * m         : 0.f;
        float a11 = (vy1 && vx1) ? wy * wx * m                 : 0.f;

        int o00 = cy0 + cx0, o01 = cy0 + cx1, o10 = cy1 + cx0, o11 = cy1 + cx1;

        const float* dwk = dwT + k * C * C;
#pragma unroll 4
        for (int cc = 0; cc < 12; ++cc) {
            int c = slice * 12 + cc;
            const float* xc = xn + c * HW;
            float s = xc[o00] * a00;
            s = fmaf(xc[o01], a01, s);
            s = fmaf(xc[o10], a10, s);
            s = fmaf(xc[o11], a11, s);
            const float* wp = dwk + c * C;   // 4-lane-shared, L1-resident
#pragma unroll
            for (int o = 0; o < C; ++o) acc[o] = fmaf(s, wp[o], acc[o]);
        }
    }

    // reduce partial sums across the 4 slices of this pixel
#pragma unroll
    for (int o = 0; o < C; ++o) {
        acc[o] += __shfl_xor(acc[o], 1);
        acc[o] += __shfl_xor(acc[o], 2);
    }

    const float* sc = ws + WS_SC;
    const float* bi = ws + WS_BI;
    int base = n * C * HW + hw;
#pragma unroll
    for (int j = 0; j < 12; ++j) {
        int o = slice * 12 + j;
        float v = fmaf(acc[o], sc[o], bi[o]) + x[base + o * HW];
        out[base + o * HW] = fmaxf(v, 0.f);
    }
}

// ---------------------------------------------------------------------------
extern "C" void kernel_launch(void* const* d_in, const int* in_sizes, int n_in,
                              void* d_out, int out_size, void* d_ws, size_t ws_size,
                              hipStream_t stream)
{
    const float* x     = (const float*)d_in[0];
    const float* tm_w  = (const float*)d_in[1];
    const float* tm_b  = (const float*)d_in[2];
    const float* tr_w  = (const float*)d_in[3];
    const float* tr_b  = (const float*)d_in[4];
    const float* mk_w  = (const float*)d_in[5];
    const float* mk_b  = (const float*)d_in[6];
    const float* dw    = (const float*)d_in[7];
    const float* gamma = (const float*)d_in[8];
    const float* beta  = (const float*)d_in[9];
    const float* rmean = (const float*)d_in[10];
    const float* rvar  = (const float*)d_in[11];
    float* out = (float*)d_out;
    float* ws  = (float*)d_ws;

    hipLaunchKernelGGL(prep_kernel, dim3((DWT_SZ + 255) / 256), dim3(256), 0, stream,
                       tm_w, tr_w, mk_w, dw, gamma, beta, rmean, rvar, ws);
    hipLaunchKernelGGL(conv15_kernel, dim3(P * 4 / 256), dim3(256), 0, stream,
                       x, tm_b, tr_b, mk_b, ws);
    hipLaunchKernelGGL(deform_kernel, dim3(P * 4 / 256), dim3(256), 0, stream,
                       x, ws, out);
}

// Round 4
// 231.740 us; speedup vs baseline: 4.2134x; 4.2134x over previous
//
#include <hip/hip_runtime.h>
#include <math.h>

namespace {
constexpr int N = 8, C = 48, H = 96, W = 72;
constexpr int HW = H * W;        // 6912
constexpr int P = N * HW;        // 55296
constexpr float BN_EPS = 1e-5f;

// ws layout (float offsets)
constexpr int WS_OY   = 0;            // 9 planes of P
constexpr int WS_OX   = 9 * P;
constexpr int WS_MK   = 18 * P;
constexpr int WS_WCAT = 27 * P;       // wcat[c][t][16]: 0..3 tm, 4..5 tr, 6..14 mk, 15 pad
constexpr int WCAT_SZ = C * 9 * 16;   // 6912
constexpr int WS_DWT  = WS_WCAT + WCAT_SZ;   // dwT[k][c][o], o contiguous
constexpr int DWT_SZ  = 9 * C * C;    // 20736
constexpr int WS_SC   = WS_DWT + DWT_SZ;     // bn scale[48]
constexpr int WS_BI   = WS_SC + C;           // bn bias2[48]
}

// ---------------------------------------------------------------------------
// Weight re-layout + BN fold.
// ---------------------------------------------------------------------------
__global__ void prep_kernel(const float* __restrict__ tm_w, const float* __restrict__ tr_w,
                            const float* __restrict__ mk_w, const float* __restrict__ dw,
                            const float* __restrict__ gamma, const float* __restrict__ beta,
                            const float* __restrict__ rmean, const float* __restrict__ rvar,
                            float* __restrict__ ws)
{
    int tid = blockIdx.x * blockDim.x + threadIdx.x;

    if (tid < WCAT_SZ) {
        int o  = tid & 15;
        int ct = tid >> 4;         // c*9 + t
        int c  = ct / 9;
        int t  = ct - c * 9;
        float v = 0.f;
        if (o < 4)       v = tm_w[(o * C + c) * 9 + t];
        else if (o < 6)  v = tr_w[((o - 4) * C + c) * 9 + t];
        else if (o < 15) v = mk_w[((o - 6) * C + c) * 9 + t];
        ws[WS_WCAT + tid] = v;
    }
    if (tid < DWT_SZ) {
        int o    = tid % C;
        int rest = tid / C;        // k*C + c
        int c    = rest % C;
        int k    = rest / C;
        ws[WS_DWT + tid] = dw[(o * C + c) * 9 + k];
    }
    if (tid < C) {
        float sc = gamma[tid] * rsqrtf(rvar[tid] + BN_EPS);
        ws[WS_SC + tid] = sc;
        ws[WS_BI + tid] = beta[tid] - rmean[tid] * sc;
    }
}

// ---------------------------------------------------------------------------
// Kernel A: 15-ch 3x3 conv. Block = 4 waves over the SAME 64 pixels; wave w
// handles input channels 12w..12w+11 (wave-uniform -> SGPR weights), then
// LDS reduce across waves. Epilogue k-taps distributed across waves.
// ---------------------------------------------------------------------------
__global__ __launch_bounds__(256) void conv15_kernel(
    const float* __restrict__ x,
    const float* __restrict__ tm_b, const float* __restrict__ tr_b,
    const float* __restrict__ mk_b,
    float* __restrict__ ws)
{
    __shared__ float red[4][16][64];   // 16 KB

    const float* wcat = ws + WS_WCAT;

    int lane = threadIdx.x & 63;
    int wv   = __builtin_amdgcn_readfirstlane(threadIdx.x >> 6);  // wave-uniform SGPR
    int pid  = blockIdx.x * 64 + lane;
    int n  = pid / HW;
    int hw = pid - n * HW;
    int h  = hw / W;
    int w  = hw - h * W;

    float acc[15];
#pragma unroll
    for (int o = 0; o < 15; ++o) acc[o] = 0.f;

    const float* xn = x + (size_t)n * C * HW;

#pragma unroll 2
    for (int cc = 0; cc < 12; ++cc) {
        int c = wv * 12 + cc;                 // wave-uniform
        const float* xc = xn + c * HW;
        float tap[9];
#pragma unroll
        for (int dy = -1; dy <= 1; ++dy) {
            int hh = h + dy;
            bool vy = (unsigned)hh < (unsigned)H;
#pragma unroll
            for (int dx = -1; dx <= 1; ++dx) {
                int ww = w + dx;
                bool v = vy && ((unsigned)ww < (unsigned)W);
                tap[(dy + 1) * 3 + (dx + 1)] = v ? xc[hh * W + ww] : 0.f;
            }
        }
#pragma unroll
        for (int t = 0; t < 9; ++t) {
            const float* wp = wcat + (c * 9 + t) * 16;   // SGPR base, s_load
            float tv = tap[t];
#pragma unroll
            for (int o = 0; o < 15; ++o) acc[o] = fmaf(tv, wp[o], acc[o]);
        }
    }

    // cross-wave reduce via LDS
#pragma unroll
    for (int o = 0; o < 15; ++o) red[wv][o][lane] = acc[o];
    __syncthreads();

    float s[15];
#pragma unroll
    for (int o = 0; o < 15; ++o)
        s[o] = red[0][o][lane] + red[1][o][lane] + red[2][o][lane] + red[3][o][lane];

    float t0 = s[0] + tm_b[0], t1 = s[1] + tm_b[1];
    float t2 = s[2] + tm_b[2], t3 = s[3] + tm_b[3];
    float r0 = s[4] + tr_b[0], r1 = s[5] + tr_b[1];

    for (int k = wv; k < 9; k += 4) {
        float ry = (float)(k / 3) - 1.f;
        float rx = (float)(k % 3) - 1.f;
        ws[WS_OY + k * P + pid] = fmaf(t0, ry, fmaf(t1, rx, r0)) - ry;
        ws[WS_OX + k * P + pid] = fmaf(t2, ry, fmaf(t3, rx, r1)) - rx;
        ws[WS_MK + k * P + pid] = s[6 + k] + mk_b[k];
    }
}

// ---------------------------------------------------------------------------
// Kernel B: deform-sample + contraction + BN + res + ReLU.
// Block = 4 waves over the SAME 64 pixels; wave w handles input channels
// 12w..12w+11 (wave-uniform weights); chunked LDS reduce (24 KB); each wave
// stores 6 output channels per chunk (coalesced).
// ---------------------------------------------------------------------------
__global__ __launch_bounds__(256) void deform_kernel(
    const float* __restrict__ x, const float* __restrict__ ws,
    float* __restrict__ out)
{
    __shared__ float red[4][24][64];   // 24 KB

    int lane = threadIdx.x & 63;
    int wv   = __builtin_amdgcn_readfirstlane(threadIdx.x >> 6);
    int pid  = blockIdx.x * 64 + lane;
    int n  = pid / HW;
    int hw = pid - n * HW;
    int h  = hw / W;
    int w  = hw - h * W;

    float acc[C];
#pragma unroll
    for (int o = 0; o < C; ++o) acc[o] = 0.f;

    const float* xn  = x + (size_t)n * C * HW;
    const float* dwT = ws + WS_DWT;

#pragma unroll 1
    for (int k = 0; k < 9; ++k) {
        float o_y = ws[WS_OY + k * P + pid];
        float o_x = ws[WS_OX + k * P + pid];
        float m   = ws[WS_MK + k * P + pid];

        float py = (float)(h + k / 3 - 1) + o_y;
        float px = (float)(w + k % 3 - 1) + o_x;

        float y0f = floorf(py), x0f = floorf(px);
        float wy = py - y0f, wx = px - x0f;
        int y0 = (int)y0f, x0 = (int)x0f;
        int y1 = y0 + 1,  x1 = x0 + 1;

        bool vy0 = (unsigned)y0 < (unsigned)H;
        bool vy1 = (unsigned)y1 < (unsigned)H;
        bool vx0 = (unsigned)x0 < (unsigned)W;
        bool vx1 = (unsigned)x1 < (unsigned)W;

        int cy0 = min(max(y0, 0), H - 1) * W;
        int cy1 = min(max(y1, 0), H - 1) * W;
        int cx0 = min(max(x0, 0), W - 1);
        int cx1 = min(max(x1, 0), W - 1);

        float a00 = (vy0 && vx0) ? (1.f - wy) * (1.f - wx) * m : 0.f;
        float a01 = (vy0 && vx1) ? (1.f - wy) * wx * m         : 0.f;
        float a10 = (vy1 && vx0) ? wy * (1.f - wx) * m         : 0.f;
        float a11 = (vy1 && vx1) ? wy * wx * m                 : 0.f;

        int o00 = cy0 + cx0, o01 = cy0 + cx1, o10 = cy1 + cx0, o11 = cy1 + cx1;

        const float* dwk = dwT + k * C * C;
#pragma unroll 2
        for (int cc = 0; cc < 12; ++cc) {
            int c = wv * 12 + cc;                 // wave-uniform
            const float* xc = xn + c * HW;
            float s = xc[o00] * a00;
            s = fmaf(xc[o01], a01, s);
            s = fmaf(xc[o10], a10, s);
            s = fmaf(xc[o11], a11, s);
            const float* wp = dwk + c * C;        // SGPR base, s_load x48
#pragma unroll
            for (int o = 0; o < C; ++o) acc[o] = fmaf(s, wp[o], acc[o]);
        }
    }

    // chunked cross-wave reduce: 2 chunks of 24 channels
    const float* sc = ws + WS_SC;
    const float* bi = ws + WS_BI;
    int base = n * C * HW + hw;

#pragma unroll
    for (int chunk = 0; chunk < 2; ++chunk) {
        if (chunk) __syncthreads();               // protect LDS reuse
#pragma unroll
        for (int j = 0; j < 24; ++j) red[wv][j][lane] = acc[chunk * 24 + j];
        __syncthreads();
#pragma unroll
        for (int j = 0; j < 6; ++j) {
            int r = wv * 6 + j;                   // row within chunk
            int o = chunk * 24 + r;               // output channel (wave-uniform)
            float v = red[0][r][lane] + red[1][r][lane] + red[2][r][lane] + red[3][r][lane];
            v = fmaf(v, sc[o], bi[o]) + x[base + o * HW];
            out[base + o * HW] = fmaxf(v, 0.f);
        }
    }
}

// ---------------------------------------------------------------------------
extern "C" void kernel_launch(void* const* d_in, const int* in_sizes, int n_in,
                              void* d_out, int out_size, void* d_ws, size_t ws_size,
                              hipStream_t stream)
{
    const float* x     = (const float*)d_in[0];
    const float* tm_w  = (const float*)d_in[1];
    const float* tm_b  = (const float*)d_in[2];
    const float* tr_w  = (const float*)d_in[3];
    const float* tr_b  = (const float*)d_in[4];
    const float* mk_w  = (const float*)d_in[5];
    const float* mk_b  = (const float*)d_in[6];
    const float* dw    = (const float*)d_in[7];
    const float* gamma = (const float*)d_in[8];
    const float* beta  = (const float*)d_in[9];
    const float* rmean = (const float*)d_in[10];
    const float* rvar  = (const float*)d_in[11];
    float* out = (float*)d_out;
    float* ws  = (float*)d_ws;

    hipLaunchKernelGGL(prep_kernel, dim3((DWT_SZ + 255) / 256), dim3(256), 0, stream,
                       tm_w, tr_w, mk_w, dw, gamma, beta, rmean, rvar, ws);
    hipLaunchKernelGGL(conv15_kernel, dim3(P / 64), dim3(256), 0, stream,
                       x, tm_b, tr_b, mk_b, ws);
    hipLaunchKernelGGL(deform_kernel, dim3(P / 64), dim3(256), 0, stream,
                       x, ws, out);
}